// Round 13
// baseline (701.141 us; speedup 1.0000x reference)
//
#include <hip/hip_runtime.h>

typedef _Float16 h16;
typedef __attribute__((ext_vector_type(4))) _Float16 h16x4;
typedef __attribute__((ext_vector_type(8))) _Float16 h16x8;
typedef __attribute__((ext_vector_type(4))) float f32x4;

#define QSCALE 0.25505653882616254f   // 32^-0.5 * log2(e)  (folded into Wq, bq)
#define LOG2E  1.4426950408889634f    // folded into biasF
#define MFMA16(a, b, c) __builtin_amdgcn_mfma_f32_16x16x16f16(a, b, c, 0, 0, 0)
#define MFMA32(a, b, c) __builtin_amdgcn_mfma_f32_16x16x32_f16(a, b, c, 0, 0, 0)

// workspace layout (bytes)
#define O_BYTES 205520896ULL              // 200704*512*2 (pre-proj output, fp16)
#define W1F_OFF (O_BYTES)                 // w1F fp16 fragment-packed: 1572864
#define W2T_OFF (W1F_OFF + 1572864ULL)    // w2T fp16 [512 out][512 k]: 524288
#define BF_OFF  (W2T_OFF + 524288ULL)     // biasF f32 frag-packed [16][4qt][4jt][64lane]x4: 262144

// ---------------- fused prep: w2 transpose | w1 fragment-pack | bias fragment-pack ----------------
__global__ __launch_bounds__(256) void wa_prep(
    const float* __restrict__ qkv_w, const float* __restrict__ proj_w,
    const float* __restrict__ table,
    h16* __restrict__ w1F, h16* __restrict__ w2T, float* __restrict__ biasF) {
  __shared__ h16 T[32][33];
  const int b = blockIdx.x, tid = threadIdx.x;
  if (b < 256) {
    int tx = tid & 31, ty = tid >> 5;
    int bo = b & 15, bc = b >> 4;
    #pragma unroll
    for (int i = 0; i < 4; ++i) {
      int c = bc * 32 + ty + 8 * i, o = bo * 32 + tx;
      T[ty + 8 * i][tx] = (h16)proj_w[c * 512 + o];
    }
    __syncthreads();
    #pragma unroll
    for (int i = 0; i < 4; ++i) {
      int o_l = ty + 8 * i;
      w2T[(size_t)(bo * 32 + o_l) * 512 + bc * 32 + tx] = T[tx][o_l];
    }
  } else if (b < 640) {
    int chunk = (b - 256) * 256 + tid;          // 98304 chunks
    int lane = chunk & 63;
    int rest = chunk >> 6;
    int f  = rest % 12;
    int kt = (rest / 12) & 7;
    int wv = (rest / 96) & 3;
    int g  = rest / 384;
    int s = f >> 2, d = (f >> 1) & 1, ks = f & 1;
    int l15 = lane & 15, lg = lane >> 4;
    int o = s * 512 + g * 128 + wv * 32 + d * 16 + l15;
    int k0 = kt * 64 + ks * 32 + lg * 8;
    float sc = (s == 0) ? QSCALE : 1.0f;
    h16x8 v;
    #pragma unroll
    for (int e = 0; e < 8; ++e)
      v[e] = (h16)(qkv_w[(size_t)(k0 + e) * 1536 + o] * sc);
    *(h16x8*)(w1F + (size_t)chunk * 8) = v;
  } else {
    int t = (b - 640) * 256 + tid;              // 16384 float4s
    int lane = t & 63, jt = (t >> 6) & 3, qt = (t >> 8) & 3, head = t >> 10;
    int l15 = lane & 15, lg = lane >> 4;
    int q = qt * 16 + l15;
    float4 v;
    #pragma unroll
    for (int r = 0; r < 4; ++r) {
      int j = jt * 16 + lg * 4 + r;
      float val = -1e30f;
      if (j < 49 && q < 49) {
        int rel = (q / 7 - j / 7 + 6) * 13 + (q % 7 - j % 7 + 6);
        val = table[rel * 16 + head] * LOG2E;
      }
      ((float*)&v)[r] = val;
    }
    ((float4*)biasF)[t] = v;
  }
}

// ---------------- fused QKV projection + window attention ----------------
// grid: 4096 windows * 2 (XCD-swizzled); block 256 = 4 waves; each block runs TWO
// head-groups sequentially over one X staging (49 real rows, 50176 B LDS; t=3 frag
// rows clamp to row 48 -- pad tokens become token-48 copies, annihilated by -1e30
// bias and the q<49 store mask). TWO GEMM passes per head: merged Q+K (shared xf
// B-operand, two accumulator sets) then V (same xf bytes as A-operand -- MFMA32
// A/B frags have identical lane maps). 128 LDS wave-reads/head vs 192 (r12) vs 64
// (r11-fused @216 regs). Peak regs ~165 -> 3 blocks/CU (512 regs/SIMD pool).
// SPILL TRIPWIRE: WRITE_SIZE must stay ~203 MB; >350 MB means allocator overflow.
// W frags = coalesced 1KB wave-loads from fragment-packed w1F, 2-deep pipelined.
// One barrier total. Softmax: max-free exp2 (log2e pre-folded), bias as QK^T C-init,
// row-sum via all-ones-A MFMA, direct O^T fragment stores.
__global__ __launch_bounds__(256, 3) void wa_qkv_attn(
    const float* __restrict__ x, const float* __restrict__ qkv_b,
    const h16* __restrict__ w1F, const float* __restrict__ biasF,
    h16* __restrict__ O) {
  __shared__ __align__(16) char lds[50176];   // X: [49 rows][64 chunks of 16B], swizzled
  const int tid = threadIdx.x;
  const int wave = tid >> 6, lane = tid & 63;
  const int l15 = lane & 15, lg = lane >> 4;
  const int sw = l15 & 7;
  const int lbid = (blockIdx.x & 7) * 1024 + (blockIdx.x >> 3);  // XCD swizzle (8192 % 8 == 0)
  const int w = lbid >> 1, gp = lbid & 1;
  const size_t rowbase = (size_t)w * 49;

  // ---- stage X: rows 0..48 fp32 -> fp16 swizzled (no pad rows) ----
  #pragma unroll
  for (int p = 0; p < 13; ++p) {
    int idx = tid + p * 256;
    if (idx < 3136) {
      int r = idx >> 6, c = idx & 63;
      const float* src = x + (rowbase + r) * 512 + c * 8;
      float4 a = *(const float4*)(src);
      float4 bb = *(const float4*)(src + 4);
      h16x8 h = { (h16)a.x, (h16)a.y, (h16)a.z, (h16)a.w,
                  (h16)bb.x, (h16)bb.y, (h16)bb.z, (h16)bb.w };
      *(h16x8*)(lds + r * 1024 + ((c ^ (r & 7)) << 4)) = h;
    }
  }
  __syncthreads();   // the only barrier in the kernel

  // per-lane X read byte-offsets (ks=0 half -> xbA, ks=1 half -> xbB);
  // t=3 clamps to row 48 (swizzle key 48&7 == 0)
  int xbA[4], xbB[4];
  #pragma unroll
  for (int t = 0; t < 4; ++t) {
    int row = (t < 3) ? (16 * t + l15) : 48;
    int swt = (t < 3) ? sw : 0;
    xbA[t] = row * 1024 + ((lg ^ swt) << 4);
    xbB[t] = row * 1024 + (((4 + lg) ^ swt) << 4);
  }
  const h16x4 ones = (h16x4){(h16)1.f, (h16)1.f, (h16)1.f, (h16)1.f};
  const float4* bF4 = (const float4*)biasF;

// load the 8 Q+K fragments (f = s*4+d*2+ks, s in {0,1}) for k-tile KT
#define WLOAD8(DST, KT) {                                                  \
    _Pragma("unroll") for (int f8 = 0; f8 < 8; ++f8)                       \
      DST[f8] = *(const h16x8*)(wb + (size_t)(KT) * 6144 + f8 * 512); }

// load the 4 V fragments (f = 8 + d*2+ks) for k-tile KT
#define WLOAD4V(DST, KT) {                                                 \
    _Pragma("unroll") for (int f4 = 0; f4 < 4; ++f4)                       \
      DST[f4] = *(const h16x8*)(wb + (size_t)(KT) * 6144 + (8 + f4) * 512); }

// one k-tile step of the merged Q+K pass: xf shared, two accumulator sets
#define STEP_QK(KT, W) {                                                   \
    h16x8 xf[4];                                                           \
    _Pragma("unroll") for (int t = 0; t < 4; ++t)                          \
      xf[t] = *(const h16x8*)(lds + xbA[t] + (KT) * 128);                  \
    __builtin_amdgcn_s_setprio(1);                                         \
    _Pragma("unroll") for (int d = 0; d < 2; ++d)                          \
    _Pragma("unroll") for (int t = 0; t < 4; ++t) {                        \
      accQ[d][t] = MFMA32(W[d*2],     xf[t], accQ[d][t]);                  \
      accK[d][t] = MFMA32(W[4 + d*2], xf[t], accK[d][t]);                  \
    }                                                                      \
    __builtin_amdgcn_s_setprio(0);                                         \
    _Pragma("unroll") for (int t = 0; t < 4; ++t)                          \
      xf[t] = *(const h16x8*)(lds + xbB[t] + (KT) * 128);                  \
    __builtin_amdgcn_s_setprio(1);                                         \
    _Pragma("unroll") for (int d = 0; d < 2; ++d)                          \
    _Pragma("unroll") for (int t = 0; t < 4; ++t) {                        \
      accQ[d][t] = MFMA32(W[d*2 + 1],     xf[t], accQ[d][t]);              \
      accK[d][t] = MFMA32(W[4 + d*2 + 1], xf[t], accK[d][t]);              \
    }                                                                      \
    __builtin_amdgcn_s_setprio(0); }

// one k-tile step of the V pass: same xf bytes, used as A-operand
#define STEP_V(KT, W) {                                                    \
    h16x8 xf[4];                                                           \
    _Pragma("unroll") for (int t = 0; t < 4; ++t)                          \
      xf[t] = *(const h16x8*)(lds + xbA[t] + (KT) * 128);                  \
    __builtin_amdgcn_s_setprio(1);                                         \
    _Pragma("unroll") for (int d = 0; d < 2; ++d)                          \
    _Pragma("unroll") for (int t = 0; t < 4; ++t)                          \
      accV[t][d] = MFMA32(xf[t], W[d*2], accV[t][d]);                      \
    __builtin_amdgcn_s_setprio(0);                                         \
    _Pragma("unroll") for (int t = 0; t < 4; ++t)                          \
      xf[t] = *(const h16x8*)(lds + xbB[t] + (KT) * 128);                  \
    __builtin_amdgcn_s_setprio(1);                                         \
    _Pragma("unroll") for (int d = 0; d < 2; ++d)                          \
    _Pragma("unroll") for (int t = 0; t < 4; ++t)                          \
      accV[t][d] = MFMA32(xf[t], W[d*2 + 1], accV[t][d]);                  \
    __builtin_amdgcn_s_setprio(0); }

#define PROCESS_HEAD(G) {                                                  \
    const int head = (G) * 4 + wave;                                       \
    const h16* wb = w1F + ((size_t)((G) * 4 + wave) * 8) * 6144 + lane * 8;\
    h16x4 Qh[2][4], Kh[2][4], Vh[4][2];                                    \
    /* ---- merged Q+K pass (shared xf) ---- */ {                          \
      f32x4 accQ[2][4], accK[2][4];                                        \
      _Pragma("unroll") for (int d = 0; d < 2; ++d)                        \
      _Pragma("unroll") for (int t = 0; t < 4; ++t) {                      \
        accQ[d][t] = (f32x4){0.f, 0.f, 0.f, 0.f};                          \
        accK[d][t] = (f32x4){0.f, 0.f, 0.f, 0.f};                          \
      }                                                                    \
      h16x8 WA[8], WB[8];                                                  \
      WLOAD8(WA, 0);                                                       \
      for (int kt2 = 0; kt2 < 4; ++kt2) {                                  \
        WLOAD8(WB, 2 * kt2 + 1);                                           \
        STEP_QK(2 * kt2, WA);                                              \
        if (kt2 < 3) WLOAD8(WA, 2 * kt2 + 2);                              \
        STEP_QK(2 * kt2 + 1, WB);                                          \
      }                                                                    \
      _Pragma("unroll") for (int d = 0; d < 2; ++d) {                      \
        float bq[4], bk[4];                                                \
        _Pragma("unroll") for (int r = 0; r < 4; ++r) {                    \
          bq[r] = qkv_b[head * 32 + 16 * d + 4 * lg + r] * QSCALE;         \
          bk[r] = qkv_b[512 + head * 32 + 16 * d + 4 * lg + r];            \
        }                                                                  \
        _Pragma("unroll") for (int t = 0; t < 4; ++t)                      \
        _Pragma("unroll") for (int r = 0; r < 4; ++r) {                    \
          Qh[d][t][r] = (h16)(accQ[d][t][r] + bq[r]);                      \
          Kh[d][t][r] = (h16)(accK[d][t][r] + bk[r]);                      \
        }                                                                  \
      }                                                                    \
    }                                                                      \
    /* ---- V pass (same xf bytes as A-operand) ---- */ {                  \
      f32x4 accV[4][2];                                                    \
      _Pragma("unroll") for (int t = 0; t < 4; ++t)                        \
      _Pragma("unroll") for (int d = 0; d < 2; ++d)                        \
        accV[t][d] = (f32x4){0.f, 0.f, 0.f, 0.f};                          \
      h16x8 VA[4], VB[4];                                                  \
      WLOAD4V(VA, 0);                                                      \
      for (int kt2 = 0; kt2 < 4; ++kt2) {                                  \
        WLOAD4V(VB, 2 * kt2 + 1);                                          \
        STEP_V(2 * kt2, VA);                                               \
        if (kt2 < 3) WLOAD4V(VA, 2 * kt2 + 2);                             \
        STEP_V(2 * kt2 + 1, VB);                                           \
      }                                                                    \
      _Pragma("unroll") for (int d = 0; d < 2; ++d) {                      \
        float bv = qkv_b[1024 + head * 32 + 16 * d + l15];                 \
        _Pragma("unroll") for (int t = 0; t < 4; ++t)                      \
        _Pragma("unroll") for (int r = 0; r < 4; ++r)                      \
          Vh[t][d][r] = (h16)(accV[t][d][r] + bv);                         \
      }                                                                    \
    }                                                                      \
    /* S^T = K Q^T with bias fragment as C-init */                         \
    f32x4 st[4][4];                                                        \
    __builtin_amdgcn_s_setprio(1);                                         \
    _Pragma("unroll") for (int jt = 0; jt < 4; ++jt)                       \
    _Pragma("unroll") for (int qt = 0; qt < 4; ++qt) {                     \
      float4 bvv = bF4[(head * 16 + qt * 4 + jt) * 64 + lane];             \
      f32x4 c0 = { bvv.x, bvv.y, bvv.z, bvv.w };                           \
      st[jt][qt] = MFMA16(Kh[0][jt], Qh[0][qt], c0);                       \
      st[jt][qt] = MFMA16(Kh[1][jt], Qh[1][qt], st[jt][qt]);               \
    }                                                                      \
    __builtin_amdgcn_s_setprio(0);                                         \
    h16x4 pf[4][4];                                                        \
    _Pragma("unroll") for (int qt = 0; qt < 4; ++qt)                       \
    _Pragma("unroll") for (int jt = 0; jt < 4; ++jt) {                     \
      h16x4 p;                                                             \
      _Pragma("unroll") for (int r = 0; r < 4; ++r)                        \
        p[r] = (h16)exp2f(st[jt][qt][r]);                                  \
      pf[jt][qt] = p;                                                      \
    }                                                                      \
    f32x4 ss[4];                                                           \
    _Pragma("unroll") for (int qt = 0; qt < 4; ++qt)                       \
      ss[qt] = (f32x4){0.f, 0.f, 0.f, 0.f};                                \
    f32x4 ot[2][4];                                                        \
    _Pragma("unroll") for (int d = 0; d < 2; ++d)                          \
    _Pragma("unroll") for (int qt = 0; qt < 4; ++qt)                       \
      ot[d][qt] = (f32x4){0.f, 0.f, 0.f, 0.f};                             \
    __builtin_amdgcn_s_setprio(1);                                         \
    _Pragma("unroll") for (int jt = 0; jt < 4; ++jt)                       \
    _Pragma("unroll") for (int qt = 0; qt < 4; ++qt) {                     \
      ss[qt] = MFMA16(ones, pf[jt][qt], ss[qt]);                           \
      _Pragma("unroll") for (int d = 0; d < 2; ++d)                        \
        ot[d][qt] = MFMA16(Vh[jt][d], pf[jt][qt], ot[d][qt]);              \
    }                                                                      \
    __builtin_amdgcn_s_setprio(0);                                         \
    _Pragma("unroll") for (int qt = 0; qt < 4; ++qt) {                     \
      int q = 16 * qt + l15;                                               \
      float ri = 1.0f / ss[qt][0];                                         \
      if (q < 49) {                                                        \
        h16* gdst = O + (rowbase + q) * 512 + head * 32 + 4 * lg;          \
        _Pragma("unroll") for (int d = 0; d < 2; ++d) {                    \
          h16x4 ov;                                                        \
          _Pragma("unroll") for (int r = 0; r < 4; ++r)                    \
            ov[r] = (h16)(ot[d][qt][r] * ri);                              \
          *(h16x4*)(gdst + 16 * d) = ov;                                   \
        }                                                                  \
      }                                                                    \
    } }

  PROCESS_HEAD(gp * 2);
  PROCESS_HEAD(gp * 2 + 1);
#undef PROCESS_HEAD
#undef STEP_QK
#undef STEP_V
#undef WLOAD8
#undef WLOAD4V
}

// ---------------- output projection: out = O @ w2 + proj_b ----------------
// 128x128 tile, 4 waves of 64x64, BK=64, x32 MFMAs, swizzled LDS, reg prefetch.
__global__ __launch_bounds__(256, 3) void wa_proj(
    const h16* __restrict__ O, const h16* __restrict__ w2T,
    const float* __restrict__ proj_b, float* __restrict__ out) {
  __shared__ __align__(16) char lds[32768];
  char* Ac = lds;            // [128 rows][64 k] h16, swizzled
  char* Bc = lds + 16384;    // [128 cols][64 k] h16, swizzled
  const int tid = threadIdx.x;
  const int wave = tid >> 6, lane = tid & 63;
  const int l15 = lane & 15, lg = lane >> 4;
  const int lbid = (blockIdx.x & 7) * 784 + (blockIdx.x >> 3);  // XCD swizzle (6272 % 8 == 0)
  const int rowt = lbid >> 2, colt = lbid & 3;
  const int wr = wave >> 1, wc = wave & 1;

  f32x4 acc[4][4];
  #pragma unroll
  for (int a = 0; a < 4; ++a)
    #pragma unroll
    for (int b = 0; b < 4; ++b) acc[a][b] = (f32x4){0.f, 0.f, 0.f, 0.f};

  h16x8 pre[8];
  #pragma unroll
  for (int p = 0; p < 8; ++p) {          // prologue load tile 0
    int idx = tid + p * 256;
    int r = (idx >> 3) & 127, c = idx & 7;
    pre[p] = (idx < 1024)
        ? *(const h16x8*)(O   + (size_t)(rowt * 128 + r) * 512 + c * 8)
        : *(const h16x8*)(w2T + (size_t)(colt * 128 + r) * 512 + c * 8);
  }
  #pragma unroll
  for (int p = 0; p < 8; ++p) {
    int idx = tid + p * 256;
    int r = (idx >> 3) & 127, c = idx & 7;
    char* dst = ((idx < 1024) ? Ac : Bc) + r * 128 + ((c ^ (r & 7)) << 4);
    *(h16x8*)dst = pre[p];
  }
  __syncthreads();

  for (int kt = 0; kt < 8; ++kt) {
    if (kt < 7) {
      #pragma unroll
      for (int p = 0; p < 8; ++p) {
        int idx = tid + p * 256;
        int r = (idx >> 3) & 127, c = idx & 7;
        pre[p] = (idx < 1024)
            ? *(const h16x8*)(O   + (size_t)(rowt * 128 + r) * 512 + (kt + 1) * 64 + c * 8)
            : *(const h16x8*)(w2T + (size_t)(colt * 128 + r) * 512 + (kt + 1) * 64 + c * 8);
      }
    }
    #pragma unroll
    for (int kh = 0; kh < 2; ++kh) {
      const int cc = kh * 4 + lg;
      const int sw = (l15 & 7);
      h16x8 af[4], bf[4];
      #pragma unroll
      for (int mt = 0; mt < 4; ++mt) {
        int r = wr * 64 + 16 * mt + l15;
        af[mt] = *(const h16x8*)(Ac + r * 128 + ((cc ^ sw) << 4));
      }
      #pragma unroll
      for (int nt = 0; nt < 4; ++nt) {
        int r = wc * 64 + 16 * nt + l15;
        bf[nt] = *(const h16x8*)(Bc + r * 128 + ((cc ^ sw) << 4));
      }
      __builtin_amdgcn_s_setprio(1);
      #pragma unroll
      for (int mt = 0; mt < 4; ++mt)
        #pragma unroll
        for (int nt = 0; nt < 4; ++nt)
          acc[mt][nt] = MFMA32(af[mt], bf[nt], acc[mt][nt]);
      __builtin_amdgcn_s_setprio(0);
    }
    __syncthreads();
    if (kt < 7) {
      #pragma unroll
      for (int p = 0; p < 8; ++p) {
        int idx = tid + p * 256;
        int r = (idx >> 3) & 127, c = idx & 7;
        char* dst = ((idx < 1024) ? Ac : Bc) + r * 128 + ((c ^ (r & 7)) << 4);
        *(h16x8*)dst = pre[p];
      }
      __syncthreads();
    }
  }
  #pragma unroll
  for (int nt = 0; nt < 4; ++nt) {
    int col = colt * 128 + wc * 64 + nt * 16 + l15;
    float pb = proj_b[col];
    #pragma unroll
    for (int mt = 0; mt < 4; ++mt) {
      int row = rowt * 128 + wr * 64 + mt * 16 + 4 * lg;
      #pragma unroll
      for (int r = 0; r < 4; ++r)
        out[(size_t)(row + r) * 512 + col] = acc[mt][nt][r] + pb;
    }
  }
}

extern "C" void kernel_launch(void* const* d_in, const int* in_sizes, int n_in,
                              void* d_out, int out_size, void* d_ws, size_t ws_size,
                              hipStream_t stream) {
  const float* x          = (const float*)d_in[0];
  const float* qkv_w      = (const float*)d_in[1];
  const float* qkv_b      = (const float*)d_in[2];
  const float* proj_w     = (const float*)d_in[3];
  const float* proj_b     = (const float*)d_in[4];
  const float* bias_table = (const float*)d_in[5];
  float* out = (float*)d_out;

  char* ws = (char*)d_ws;
  h16*   O     = (h16*)ws;
  h16*   w1F   = (h16*)(ws + W1F_OFF);
  h16*   w2T   = (h16*)(ws + W2T_OFF);
  float* biasF = (float*)(ws + BF_OFF);

  wa_prep<<<704, 256, 0, stream>>>(qkv_w, proj_w, bias_table, w1F, w2T, biasF);
  wa_qkv_attn<<<8192, 256, 0, stream>>>(x, qkv_b, w1F, biasF, O);
  wa_proj<<<1568 * 4, 256, 0, stream>>>(O, w2T, proj_b, out);
}

// Round 14
// 699.263 us; speedup vs baseline: 1.0027x; 1.0027x over previous
//
#include <hip/hip_runtime.h>

typedef _Float16 h16;
typedef __attribute__((ext_vector_type(4))) _Float16 h16x4;
typedef __attribute__((ext_vector_type(8))) _Float16 h16x8;
typedef __attribute__((ext_vector_type(4))) float f32x4;

#define QSCALE 0.25505653882616254f   // 32^-0.5 * log2(e)  (folded into Wq, bq)
#define LOG2E  1.4426950408889634f    // folded into biasF
#define MFMA16(a, b, c) __builtin_amdgcn_mfma_f32_16x16x16f16(a, b, c, 0, 0, 0)
#define MFMA32(a, b, c) __builtin_amdgcn_mfma_f32_16x16x32_f16(a, b, c, 0, 0, 0)

// workspace layout (bytes)
#define O_BYTES 205520896ULL              // 200704*512*2 (pre-proj output, fp16)
#define W1F_OFF (O_BYTES)                 // w1F fp16 fragment-packed: 1572864
#define W2F_OFF (W1F_OFF + 1572864ULL)    // w2F fp16 fragment-packed: 524288
#define BF_OFF  (W2F_OFF + 524288ULL)     // biasF f32 frag-packed [16][4qt][4jt][64lane]x4: 262144

// ---------------- fused prep: w2 fragment-pack | w1 fragment-pack | bias fragment-pack ----------------
// blocks 0..127: proj_w [512k][512o] -> w2F chunks ((cw*8+kt)*8 + nt*2+kh)*64+lane (8 h16);
//   lane holds o = cw*64 + nt*16 + l15, k = kt*64 + (kh*4+lg)*8 + e  (cw = colt*2+wc).
// blocks 128..511: qkv_w [512k][1536o] -> w1F chunks (((g*4+wv)*8+kt)*12+f)*64+lane;
//   f = s*4+d*2+ks; o = s*512+g*128+wv*32+d*16+l15; k = kt*64+ks*32+lg*8..+7; Q rows x QSCALE.
// blocks 512..575: bias_table -> biasF float4[(head*16+qt*4+jt)*64+lane]; j=16jt+4lg+r, q=16qt+l15;
//   value = table[rel(q,j)][head]*LOG2E, -1e30 where padded. Every wave-load = contiguous 1KB.
__global__ __launch_bounds__(256) void wa_prep(
    const float* __restrict__ qkv_w, const float* __restrict__ proj_w,
    const float* __restrict__ table,
    h16* __restrict__ w1F, h16* __restrict__ w2F, float* __restrict__ biasF) {
  const int b = blockIdx.x, tid = threadIdx.x;
  if (b < 128) {
    int chunk = b * 256 + tid;                  // 32768 chunks
    int lane = chunk & 63;
    int rest = chunk >> 6;
    int fr = rest & 7, kt = (rest >> 3) & 7, cw = rest >> 6;
    int nt = fr >> 1, kh = fr & 1;
    int l15 = lane & 15, lg = lane >> 4;
    int o = cw * 64 + nt * 16 + l15;
    int k0 = kt * 64 + (kh * 4 + lg) * 8;
    h16x8 v;
    #pragma unroll
    for (int e = 0; e < 8; ++e)
      v[e] = (h16)proj_w[(size_t)(k0 + e) * 512 + o];
    *(h16x8*)(w2F + (size_t)chunk * 8) = v;
  } else if (b < 512) {
    int chunk = (b - 128) * 256 + tid;          // 98304 chunks
    int lane = chunk & 63;
    int rest = chunk >> 6;
    int f  = rest % 12;
    int kt = (rest / 12) & 7;
    int wv = (rest / 96) & 3;
    int g  = rest / 384;
    int s = f >> 2, d = (f >> 1) & 1, ks = f & 1;
    int l15 = lane & 15, lg = lane >> 4;
    int o = s * 512 + g * 128 + wv * 32 + d * 16 + l15;
    int k0 = kt * 64 + ks * 32 + lg * 8;
    float sc = (s == 0) ? QSCALE : 1.0f;
    h16x8 v;
    #pragma unroll
    for (int e = 0; e < 8; ++e)
      v[e] = (h16)(qkv_w[(size_t)(k0 + e) * 1536 + o] * sc);
    *(h16x8*)(w1F + (size_t)chunk * 8) = v;
  } else {
    int t = (b - 512) * 256 + tid;              // 16384 float4s
    int lane = t & 63, jt = (t >> 6) & 3, qt = (t >> 8) & 3, head = t >> 10;
    int l15 = lane & 15, lg = lane >> 4;
    int q = qt * 16 + l15;
    float4 v;
    #pragma unroll
    for (int r = 0; r < 4; ++r) {
      int j = jt * 16 + lg * 4 + r;
      float val = -1e30f;
      if (j < 49 && q < 49) {
        int rel = (q / 7 - j / 7 + 6) * 13 + (q % 7 - j % 7 + 6);
        val = table[rel * 16 + head] * LOG2E;
      }
      ((float*)&v)[r] = val;
    }
    ((float4*)biasF)[t] = v;
  }
}

// ---------------- fused QKV projection + window attention ----------------
// grid: 4096 windows * 2 (XCD-swizzled); block 256 = 4 waves; each block runs TWO
// head-groups sequentially over one X staging (49 real rows, 50176 B LDS; t=3 frag
// rows clamp to row 48 -- pad tokens become token-48 copies, annihilated by -1e30
// bias and the q<49 store mask). Two GEMM passes per head: merged Q+K (shared xf),
// then V (same xf bytes as A-operand). W loads SINGLE-BUFFERED with #pragma unroll 1
// (r13 lesson: 2-deep W dbuf in the merged pass -> ~180 regs -> scratch spill,
// WRITE 202->245 MB; L2 latency is covered by 3 waves/SIMD TLP instead).
// SPILL TRIPWIRE: WRITE_SIZE ~202 MB. Peak regs ~150 -> 3 blocks/CU (512 regs/SIMD).
// One barrier total. Softmax: max-free exp2 (log2e pre-folded), bias as QK^T C-init,
// row-sum via all-ones-A MFMA, direct O^T fragment stores.
__global__ __launch_bounds__(256, 3) void wa_qkv_attn(
    const float* __restrict__ x, const float* __restrict__ qkv_b,
    const h16* __restrict__ w1F, const float* __restrict__ biasF,
    h16* __restrict__ O) {
  __shared__ __align__(16) char lds[50176];   // X: [49 rows][64 chunks of 16B], swizzled
  const int tid = threadIdx.x;
  const int wave = tid >> 6, lane = tid & 63;
  const int l15 = lane & 15, lg = lane >> 4;
  const int sw = l15 & 7;
  const int lbid = (blockIdx.x & 7) * 1024 + (blockIdx.x >> 3);  // XCD swizzle (8192 % 8 == 0)
  const int w = lbid >> 1, gp = lbid & 1;
  const size_t rowbase = (size_t)w * 49;

  // ---- stage X: rows 0..48 fp32 -> fp16 swizzled (no pad rows) ----
  #pragma unroll
  for (int p = 0; p < 13; ++p) {
    int idx = tid + p * 256;
    if (idx < 3136) {
      int r = idx >> 6, c = idx & 63;
      const float* src = x + (rowbase + r) * 512 + c * 8;
      float4 a = *(const float4*)(src);
      float4 bb = *(const float4*)(src + 4);
      h16x8 h = { (h16)a.x, (h16)a.y, (h16)a.z, (h16)a.w,
                  (h16)bb.x, (h16)bb.y, (h16)bb.z, (h16)bb.w };
      *(h16x8*)(lds + r * 1024 + ((c ^ (r & 7)) << 4)) = h;
    }
  }
  __syncthreads();   // the only barrier in the kernel

  // per-lane X read byte-offsets; t=3 clamps to row 48 (swizzle key 48&7 == 0)
  int xbA[4], xbB[4];
  #pragma unroll
  for (int t = 0; t < 4; ++t) {
    int row = (t < 3) ? (16 * t + l15) : 48;
    int swt = (t < 3) ? sw : 0;
    xbA[t] = row * 1024 + ((lg ^ swt) << 4);
    xbB[t] = row * 1024 + (((4 + lg) ^ swt) << 4);
  }
  const h16x4 ones = (h16x4){(h16)1.f, (h16)1.f, (h16)1.f, (h16)1.f};
  const float4* bF4 = (const float4*)biasF;

#define WLOAD8(DST, KT) {                                                  \
    _Pragma("unroll") for (int f8 = 0; f8 < 8; ++f8)                       \
      DST[f8] = *(const h16x8*)(wb + (size_t)(KT) * 6144 + f8 * 512); }

#define WLOAD4V(DST, KT) {                                                 \
    _Pragma("unroll") for (int f4 = 0; f4 < 4; ++f4)                       \
      DST[f4] = *(const h16x8*)(wb + (size_t)(KT) * 6144 + (8 + f4) * 512); }

#define STEP_QK(KT, W) {                                                   \
    h16x8 xf[4];                                                           \
    _Pragma("unroll") for (int t = 0; t < 4; ++t)                          \
      xf[t] = *(const h16x8*)(lds + xbA[t] + (KT) * 128);                  \
    __builtin_amdgcn_s_setprio(1);                                         \
    _Pragma("unroll") for (int d = 0; d < 2; ++d)                          \
    _Pragma("unroll") for (int t = 0; t < 4; ++t) {                        \
      accQ[d][t] = MFMA32(W[d*2],     xf[t], accQ[d][t]);                  \
      accK[d][t] = MFMA32(W[4 + d*2], xf[t], accK[d][t]);                  \
    }                                                                      \
    __builtin_amdgcn_s_setprio(0);                                         \
    _Pragma("unroll") for (int t = 0; t < 4; ++t)                          \
      xf[t] = *(const h16x8*)(lds + xbB[t] + (KT) * 128);                  \
    __builtin_amdgcn_s_setprio(1);                                         \
    _Pragma("unroll") for (int d = 0; d < 2; ++d)                          \
    _Pragma("unroll") for (int t = 0; t < 4; ++t) {                        \
      accQ[d][t] = MFMA32(W[d*2 + 1],     xf[t], accQ[d][t]);              \
      accK[d][t] = MFMA32(W[4 + d*2 + 1], xf[t], accK[d][t]);              \
    }                                                                      \
    __builtin_amdgcn_s_setprio(0); }

#define STEP_V(KT, W) {                                                    \
    h16x8 xf[4];                                                           \
    _Pragma("unroll") for (int t = 0; t < 4; ++t)                          \
      xf[t] = *(const h16x8*)(lds + xbA[t] + (KT) * 128);                  \
    __builtin_amdgcn_s_setprio(1);                                         \
    _Pragma("unroll") for (int d = 0; d < 2; ++d)                          \
    _Pragma("unroll") for (int t = 0; t < 4; ++t)                          \
      accV[t][d] = MFMA32(xf[t], W[d*2], accV[t][d]);                      \
    __builtin_amdgcn_s_setprio(0);                                         \
    _Pragma("unroll") for (int t = 0; t < 4; ++t)                          \
      xf[t] = *(const h16x8*)(lds + xbB[t] + (KT) * 128);                  \
    __builtin_amdgcn_s_setprio(1);                                         \
    _Pragma("unroll") for (int d = 0; d < 2; ++d)                          \
    _Pragma("unroll") for (int t = 0; t < 4; ++t)                          \
      accV[t][d] = MFMA32(xf[t], W[d*2 + 1], accV[t][d]);                  \
    __builtin_amdgcn_s_setprio(0); }

#define PROCESS_HEAD(G) {                                                  \
    const int head = (G) * 4 + wave;                                       \
    const h16* wb = w1F + ((size_t)((G) * 4 + wave) * 8) * 6144 + lane * 8;\
    h16x4 Qh[2][4], Kh[2][4], Vh[4][2];                                    \
    /* ---- merged Q+K pass (shared xf, single-buffered W) ---- */ {       \
      f32x4 accQ[2][4], accK[2][4];                                        \
      _Pragma("unroll") for (int d = 0; d < 2; ++d)                        \
      _Pragma("unroll") for (int t = 0; t < 4; ++t) {                      \
        accQ[d][t] = (f32x4){0.f, 0.f, 0.f, 0.f};                          \
        accK[d][t] = (f32x4){0.f, 0.f, 0.f, 0.f};                          \
      }                                                                    \
      _Pragma("unroll 1") for (int kt = 0; kt < 8; ++kt) {                 \
        h16x8 WQK[8];                                                      \
        WLOAD8(WQK, kt);                                                   \
        STEP_QK(kt, WQK);                                                  \
      }                                                                    \
      _Pragma("unroll") for (int d = 0; d < 2; ++d) {                      \
        float bq[4], bk[4];                                                \
        _Pragma("unroll") for (int r = 0; r < 4; ++r) {                    \
          bq[r] = qkv_b[head * 32 + 16 * d + 4 * lg + r] * QSCALE;         \
          bk[r] = qkv_b[512 + head * 32 + 16 * d + 4 * lg + r];            \
        }                                                                  \
        _Pragma("unroll") for (int t = 0; t < 4; ++t)                      \
        _Pragma("unroll") for (int r = 0; r < 4; ++r) {                    \
          Qh[d][t][r] = (h16)(accQ[d][t][r] + bq[r]);                      \
          Kh[d][t][r] = (h16)(accK[d][t][r] + bk[r]);                      \
        }                                                                  \
      }                                                                    \
    }                                                                      \
    /* ---- V pass (same xf bytes as A-operand, single-buffered W) ---- */ { \
      f32x4 accV[4][2];                                                    \
      _Pragma("unroll") for (int t = 0; t < 4; ++t)                        \
      _Pragma("unroll") for (int d = 0; d < 2; ++d)                        \
        accV[t][d] = (f32x4){0.f, 0.f, 0.f, 0.f};                          \
      _Pragma("unroll 1") for (int kt = 0; kt < 8; ++kt) {                 \
        h16x8 WV[4];                                                       \
        WLOAD4V(WV, kt);                                                   \
        STEP_V(kt, WV);                                                    \
      }                                                                    \
      _Pragma("unroll") for (int d = 0; d < 2; ++d) {                      \
        float bv = qkv_b[1024 + head * 32 + 16 * d + l15];                 \
        _Pragma("unroll") for (int t = 0; t < 4; ++t)                      \
        _Pragma("unroll") for (int r = 0; r < 4; ++r)                      \
          Vh[t][d][r] = (h16)(accV[t][d][r] + bv);                         \
      }                                                                    \
    }                                                                      \
    /* S^T = K Q^T with bias fragment as C-init */                         \
    f32x4 st[4][4];                                                        \
    __builtin_amdgcn_s_setprio(1);                                         \
    _Pragma("unroll") for (int jt = 0; jt < 4; ++jt)                       \
    _Pragma("unroll") for (int qt = 0; qt < 4; ++qt) {                     \
      float4 bvv = bF4[(head * 16 + qt * 4 + jt) * 64 + lane];             \
      f32x4 c0 = { bvv.x, bvv.y, bvv.z, bvv.w };                           \
      st[jt][qt] = MFMA16(Kh[0][jt], Qh[0][qt], c0);                       \
      st[jt][qt] = MFMA16(Kh[1][jt], Qh[1][qt], st[jt][qt]);               \
    }                                                                      \
    __builtin_amdgcn_s_setprio(0);                                         \
    h16x4 pf[4][4];                                                        \
    _Pragma("unroll") for (int qt = 0; qt < 4; ++qt)                       \
    _Pragma("unroll") for (int jt = 0; jt < 4; ++jt) {                     \
      h16x4 p;                                                             \
      _Pragma("unroll") for (int r = 0; r < 4; ++r)                        \
        p[r] = (h16)exp2f(st[jt][qt][r]);                                  \
      pf[jt][qt] = p;                                                      \
    }                                                                      \
    f32x4 ss[4];                                                           \
    _Pragma("unroll") for (int qt = 0; qt < 4; ++qt)                       \
      ss[qt] = (f32x4){0.f, 0.f, 0.f, 0.f};                                \
    f32x4 ot[2][4];                                                        \
    _Pragma("unroll") for (int d = 0; d < 2; ++d)                          \
    _Pragma("unroll") for (int qt = 0; qt < 4; ++qt)                       \
      ot[d][qt] = (f32x4){0.f, 0.f, 0.f, 0.f};                             \
    __builtin_amdgcn_s_setprio(1);                                         \
    _Pragma("unroll") for (int jt = 0; jt < 4; ++jt)                       \
    _Pragma("unroll") for (int qt = 0; qt < 4; ++qt) {                     \
      ss[qt] = MFMA16(ones, pf[jt][qt], ss[qt]);                           \
      _Pragma("unroll") for (int d = 0; d < 2; ++d)                        \
        ot[d][qt] = MFMA16(Vh[jt][d], pf[jt][qt], ot[d][qt]);              \
    }                                                                      \
    __builtin_amdgcn_s_setprio(0);                                         \
    _Pragma("unroll") for (int qt = 0; qt < 4; ++qt) {                     \
      int q = 16 * qt + l15;                                               \
      float ri = 1.0f / ss[qt][0];                                         \
      if (q < 49) {                                                        \
        h16* gdst = O + (rowbase + q) * 512 + head * 32 + 4 * lg;          \
        _Pragma("unroll") for (int d = 0; d < 2; ++d) {                    \
          h16x4 ov;                                                        \
          _Pragma("unroll") for (int r = 0; r < 4; ++r)                    \
            ov[r] = (h16)(ot[d][qt][r] * ri);                              \
          *(h16x4*)(gdst + 16 * d) = ov;                                   \
        }                                                                  \
      }                                                                    \
    } }

  PROCESS_HEAD(gp * 2);
  PROCESS_HEAD(gp * 2 + 1);
#undef PROCESS_HEAD
#undef STEP_QK
#undef STEP_V
#undef WLOAD8
#undef WLOAD4V
}

// ---------------- output projection: out = O @ w2 + proj_b ----------------
// 128x128 tile, 4 waves of 64x64, BK=64, x32 MFMAs. A (O tile) staged in LDS
// (swizzled, 16 KiB); B read DIRECTLY from fragment-packed w2F (L2-resident,
// coalesced 1KB wave-loads) -- no B staging, half the barrier-bound LDS traffic.
__global__ __launch_bounds__(256, 3) void wa_proj(
    const h16* __restrict__ O, const h16* __restrict__ w2F,
    const float* __restrict__ proj_b, float* __restrict__ out) {
  __shared__ __align__(16) char lds[16384];   // A: [128 rows][64 k] h16, swizzled
  const int tid = threadIdx.x;
  const int wave = tid >> 6, lane = tid & 63;
  const int l15 = lane & 15, lg = lane >> 4;
  const int lbid = (blockIdx.x & 7) * 784 + (blockIdx.x >> 3);  // XCD swizzle (6272 % 8 == 0)
  const int rowt = lbid >> 2, colt = lbid & 3;
  const int wr = wave >> 1, wc = wave & 1;
  // per-lane w2F base for this wave's column half (cw = colt*2+wc)
  const h16* wb2 = w2F + (size_t)(colt * 2 + wc) * 32768 + lane * 8;

  f32x4 acc[4][4];
  #pragma unroll
  for (int a = 0; a < 4; ++a)
    #pragma unroll
    for (int b = 0; b < 4; ++b) acc[a][b] = (f32x4){0.f, 0.f, 0.f, 0.f};

  h16x8 pre[4];
  #pragma unroll
  for (int p = 0; p < 4; ++p) {          // prologue load A tile 0 (1024 chunks)
    int idx = tid + p * 256;
    int r = idx >> 3, c = idx & 7;
    pre[p] = *(const h16x8*)(O + (size_t)(rowt * 128 + r) * 512 + c * 8);
  }
  #pragma unroll
  for (int p = 0; p < 4; ++p) {
    int idx = tid + p * 256;
    int r = idx >> 3, c = idx & 7;
    *(h16x8*)(lds + r * 128 + ((c ^ (r & 7)) << 4)) = pre[p];
  }
  __syncthreads();

  for (int kt = 0; kt < 8; ++kt) {
    if (kt < 7) {
      #pragma unroll
      for (int p = 0; p < 4; ++p) {
        int idx = tid + p * 256;
        int r = idx >> 3, c = idx & 7;
        pre[p] = *(const h16x8*)(O + (size_t)(rowt * 128 + r) * 512 + (kt + 1) * 64 + c * 8);
      }
    }
    #pragma unroll
    for (int kh = 0; kh < 2; ++kh) {
      const int sw = (l15 & 7);
      h16x8 af[4], bf[4];
      #pragma unroll
      for (int mt = 0; mt < 4; ++mt) {
        int r = wr * 64 + 16 * mt + l15;
        af[mt] = *(const h16x8*)(lds + r * 128 + (((kh * 4 + lg) ^ sw) << 4));
      }
      #pragma unroll
      for (int nt = 0; nt < 4; ++nt)
        bf[nt] = *(const h16x8*)(wb2 + (size_t)(kt * 8 + nt * 2 + kh) * 512);
      __builtin_amdgcn_s_setprio(1);
      #pragma unroll
      for (int mt = 0; mt < 4; ++mt)
        #pragma unroll
        for (int nt = 0; nt < 4; ++nt)
          acc[mt][nt] = MFMA32(af[mt], bf[nt], acc[mt][nt]);
      __builtin_amdgcn_s_setprio(0);
    }
    __syncthreads();
    if (kt < 7) {
      #pragma unroll
      for (int p = 0; p < 4; ++p) {
        int idx = tid + p * 256;
        int r = idx >> 3, c = idx & 7;
        *(h16x8*)(lds + r * 128 + ((c ^ (r & 7)) << 4)) = pre[p];
      }
      __syncthreads();
    }
  }
  #pragma unroll
  for (int nt = 0; nt < 4; ++nt) {
    int col = colt * 128 + wc * 64 + nt * 16 + l15;
    float pb = proj_b[col];
    #pragma unroll
    for (int mt = 0; mt < 4; ++mt) {
      int row = rowt * 128 + wr * 64 + mt * 16 + 4 * lg;
      #pragma unroll
      for (int r = 0; r < 4; ++r)
        out[(size_t)(row + r) * 512 + col] = acc[mt][nt][r] + pb;
    }
  }
}

extern "C" void kernel_launch(void* const* d_in, const int* in_sizes, int n_in,
                              void* d_out, int out_size, void* d_ws, size_t ws_size,
                              hipStream_t stream) {
  const float* x          = (const float*)d_in[0];
  const float* qkv_w      = (const float*)d_in[1];
  const float* qkv_b      = (const float*)d_in[2];
  const float* proj_w     = (const float*)d_in[3];
  const float* proj_b     = (const float*)d_in[4];
  const float* bias_table = (const float*)d_in[5];
  float* out = (float*)d_out;

  char* ws = (char*)d_ws;
  h16*   O     = (h16*)ws;
  h16*   w1F   = (h16*)(ws + W1F_OFF);
  h16*   w2F   = (h16*)(ws + W2F_OFF);
  float* biasF = (float*)(ws + BF_OFF);

  wa_prep<<<576, 256, 0, stream>>>(qkv_w, proj_w, bias_table, w1F, w2F, biasF);
  wa_qkv_attn<<<8192, 256, 0, stream>>>(x, qkv_b, w1F, biasF, O);
  wa_proj<<<1568 * 4, 256, 0, stream>>>(O, w2F, proj_b, out);
}

// Round 15
// 696.176 us; speedup vs baseline: 1.0071x; 1.0044x over previous
//
#include <hip/hip_runtime.h>

typedef _Float16 h16;
typedef __attribute__((ext_vector_type(4))) _Float16 h16x4;
typedef __attribute__((ext_vector_type(8))) _Float16 h16x8;
typedef __attribute__((ext_vector_type(4))) float f32x4;

#define QSCALE 0.25505653882616254f   // 32^-0.5 * log2(e)  (folded into Wq, bq)
#define LOG2E  1.4426950408889634f    // folded into biasF
#define MFMA16(a, b, c) __builtin_amdgcn_mfma_f32_16x16x16f16(a, b, c, 0, 0, 0)
#define MFMA32(a, b, c) __builtin_amdgcn_mfma_f32_16x16x32_f16(a, b, c, 0, 0, 0)

// workspace layout (bytes)
#define O_BYTES 205520896ULL              // 200704*512*2 (pre-proj output, fp16)
#define W1F_OFF (O_BYTES)                 // w1F fp16 fragment-packed: 1572864
#define W2F_OFF (W1F_OFF + 1572864ULL)    // w2F fp16 fragment-packed: 524288
#define BF_OFF  (W2F_OFF + 524288ULL)     // biasF f32 frag-packed [16][4qt][4jt][64lane]x4: 262144

// ---------------- fused prep: w2 fragment-pack | w1 fragment-pack | bias fragment-pack ----------------
__global__ __launch_bounds__(256) void wa_prep(
    const float* __restrict__ qkv_w, const float* __restrict__ proj_w,
    const float* __restrict__ table,
    h16* __restrict__ w1F, h16* __restrict__ w2F, float* __restrict__ biasF) {
  const int b = blockIdx.x, tid = threadIdx.x;
  if (b < 128) {
    int chunk = b * 256 + tid;                  // 32768 chunks
    int lane = chunk & 63;
    int rest = chunk >> 6;
    int fr = rest & 7, kt = (rest >> 3) & 7, cw = rest >> 6;
    int nt = fr >> 1, kh = fr & 1;
    int l15 = lane & 15, lg = lane >> 4;
    int o = cw * 64 + nt * 16 + l15;
    int k0 = kt * 64 + (kh * 4 + lg) * 8;
    h16x8 v;
    #pragma unroll
    for (int e = 0; e < 8; ++e)
      v[e] = (h16)proj_w[(size_t)(k0 + e) * 512 + o];
    *(h16x8*)(w2F + (size_t)chunk * 8) = v;
  } else if (b < 512) {
    int chunk = (b - 128) * 256 + tid;          // 98304 chunks
    int lane = chunk & 63;
    int rest = chunk >> 6;
    int f  = rest % 12;
    int kt = (rest / 12) & 7;
    int wv = (rest / 96) & 3;
    int g  = rest / 384;
    int s = f >> 2, d = (f >> 1) & 1, ks = f & 1;
    int l15 = lane & 15, lg = lane >> 4;
    int o = s * 512 + g * 128 + wv * 32 + d * 16 + l15;
    int k0 = kt * 64 + ks * 32 + lg * 8;
    float sc = (s == 0) ? QSCALE : 1.0f;
    h16x8 v;
    #pragma unroll
    for (int e = 0; e < 8; ++e)
      v[e] = (h16)(qkv_w[(size_t)(k0 + e) * 1536 + o] * sc);
    *(h16x8*)(w1F + (size_t)chunk * 8) = v;
  } else {
    int t = (b - 512) * 256 + tid;              // 16384 float4s
    int lane = t & 63, jt = (t >> 6) & 3, qt = (t >> 8) & 3, head = t >> 10;
    int l15 = lane & 15, lg = lane >> 4;
    int q = qt * 16 + l15;
    float4 v;
    #pragma unroll
    for (int r = 0; r < 4; ++r) {
      int j = jt * 16 + lg * 4 + r;
      float val = -1e30f;
      if (j < 49 && q < 49) {
        int rel = (q / 7 - j / 7 + 6) * 13 + (q % 7 - j % 7 + 6);
        val = table[rel * 16 + head] * LOG2E;
      }
      ((float*)&v)[r] = val;
    }
    ((float4*)biasF)[t] = v;
  }
}

// ---------------- fused QKV projection + window attention ----------------
// grid: 4096 windows * 2 (XCD-swizzled); block 256 = 4 waves; each block runs TWO
// head-groups sequentially over one X staging (49 real rows, 50176 B LDS; t=3 frag
// rows clamp to row 48 -- pad tokens become token-48 copies, annihilated by -1e30
// bias and the q<49 store mask). Two GEMM passes per head: merged Q+K (shared xf),
// then V (same xf bytes as A-operand), W single-buffered (r13: dbuf spilled).
// ALL biases (qkv_b AND attention bias) folded into MFMA C-inits -- zero epilogue
// adds. Softmax: max-free exp2 (log2e pre-folded), row-sum via all-ones-A MFMA,
// rcp via v_rcp_f32, direct O^T fragment stores. One barrier total.
// SPILL TRIPWIRE: WRITE_SIZE ~208 MB. 3 blocks/CU (512 regs/SIMD pool, ~158/wave).
__global__ __launch_bounds__(256, 3) void wa_qkv_attn(
    const float* __restrict__ x, const float* __restrict__ qkv_b,
    const h16* __restrict__ w1F, const float* __restrict__ biasF,
    h16* __restrict__ O) {
  __shared__ __align__(16) char lds[50176];   // X: [49 rows][64 chunks of 16B], swizzled
  const int tid = threadIdx.x;
  const int wave = tid >> 6, lane = tid & 63;
  const int l15 = lane & 15, lg = lane >> 4;
  const int sw = l15 & 7;
  const int lbid = (blockIdx.x & 7) * 1024 + (blockIdx.x >> 3);  // XCD swizzle (8192 % 8 == 0)
  const int w = lbid >> 1, gp = lbid & 1;
  const size_t rowbase = (size_t)w * 49;

  // ---- stage X: rows 0..48 fp32 -> fp16 swizzled (no pad rows) ----
  #pragma unroll
  for (int p = 0; p < 13; ++p) {
    int idx = tid + p * 256;
    if (idx < 3136) {
      int r = idx >> 6, c = idx & 63;
      const float* src = x + (rowbase + r) * 512 + c * 8;
      float4 a = *(const float4*)(src);
      float4 bb = *(const float4*)(src + 4);
      h16x8 h = { (h16)a.x, (h16)a.y, (h16)a.z, (h16)a.w,
                  (h16)bb.x, (h16)bb.y, (h16)bb.z, (h16)bb.w };
      *(h16x8*)(lds + r * 1024 + ((c ^ (r & 7)) << 4)) = h;
    }
  }
  __syncthreads();   // the only barrier in the kernel

  // per-lane X read byte-offsets; t=3 clamps to row 48 (swizzle key 48&7 == 0)
  int xbA[4], xbB[4];
  #pragma unroll
  for (int t = 0; t < 4; ++t) {
    int row = (t < 3) ? (16 * t + l15) : 48;
    int swt = (t < 3) ? sw : 0;
    xbA[t] = row * 1024 + ((lg ^ swt) << 4);
    xbB[t] = row * 1024 + (((4 + lg) ^ swt) << 4);
  }
  const h16x4 ones = (h16x4){(h16)1.f, (h16)1.f, (h16)1.f, (h16)1.f};
  const float4* bF4 = (const float4*)biasF;

#define WLOAD8(DST, KT) {                                                  \
    _Pragma("unroll") for (int f8 = 0; f8 < 8; ++f8)                       \
      DST[f8] = *(const h16x8*)(wb + (size_t)(KT) * 6144 + f8 * 512); }

#define WLOAD4V(DST, KT) {                                                 \
    _Pragma("unroll") for (int f4 = 0; f4 < 4; ++f4)                       \
      DST[f4] = *(const h16x8*)(wb + (size_t)(KT) * 6144 + (8 + f4) * 512); }

#define STEP_QK(KT, W) {                                                   \
    h16x8 xf[4];                                                           \
    _Pragma("unroll") for (int t = 0; t < 4; ++t)                          \
      xf[t] = *(const h16x8*)(lds + xbA[t] + (KT) * 128);                  \
    __builtin_amdgcn_s_setprio(1);                                         \
    _Pragma("unroll") for (int d = 0; d < 2; ++d)                          \
    _Pragma("unroll") for (int t = 0; t < 4; ++t) {                        \
      accQ[d][t] = MFMA32(W[d*2],     xf[t], accQ[d][t]);                  \
      accK[d][t] = MFMA32(W[4 + d*2], xf[t], accK[d][t]);                  \
    }                                                                      \
    __builtin_amdgcn_s_setprio(0);                                         \
    _Pragma("unroll") for (int t = 0; t < 4; ++t)                          \
      xf[t] = *(const h16x8*)(lds + xbB[t] + (KT) * 128);                  \
    __builtin_amdgcn_s_setprio(1);                                         \
    _Pragma("unroll") for (int d = 0; d < 2; ++d)                          \
    _Pragma("unroll") for (int t = 0; t < 4; ++t) {                        \
      accQ[d][t] = MFMA32(W[d*2 + 1],     xf[t], accQ[d][t]);              \
      accK[d][t] = MFMA32(W[4 + d*2 + 1], xf[t], accK[d][t]);              \
    }                                                                      \
    __builtin_amdgcn_s_setprio(0); }

#define STEP_V(KT, W) {                                                    \
    h16x8 xf[4];                                                           \
    _Pragma("unroll") for (int t = 0; t < 4; ++t)                          \
      xf[t] = *(const h16x8*)(lds + xbA[t] + (KT) * 128);                  \
    __builtin_amdgcn_s_setprio(1);                                         \
    _Pragma("unroll") for (int d = 0; d < 2; ++d)                          \
    _Pragma("unroll") for (int t = 0; t < 4; ++t)                          \
      accV[t][d] = MFMA32(xf[t], W[d*2], accV[t][d]);                      \
    __builtin_amdgcn_s_setprio(0);                                         \
    _Pragma("unroll") for (int t = 0; t < 4; ++t)                          \
      xf[t] = *(const h16x8*)(lds + xbB[t] + (KT) * 128);                  \
    __builtin_amdgcn_s_setprio(1);                                         \
    _Pragma("unroll") for (int d = 0; d < 2; ++d)                          \
    _Pragma("unroll") for (int t = 0; t < 4; ++t)                          \
      accV[t][d] = MFMA32(xf[t], W[d*2 + 1], accV[t][d]);                  \
    __builtin_amdgcn_s_setprio(0); }

#define PROCESS_HEAD(G) {                                                  \
    const int head = (G) * 4 + wave;                                       \
    const h16* wb = w1F + ((size_t)((G) * 4 + wave) * 8) * 6144 + lane * 8;\
    h16x4 Qh[2][4], Kh[2][4], Vh[4][2];                                    \
    /* ---- merged Q+K pass (bias C-init, shared xf, single-buffered W) */ {\
      f32x4 accQ[2][4], accK[2][4];                                        \
      _Pragma("unroll") for (int d = 0; d < 2; ++d) {                      \
        f32x4 iq, ik;                                                      \
        _Pragma("unroll") for (int r = 0; r < 4; ++r) {                    \
          iq[r] = qkv_b[head * 32 + 16 * d + 4 * lg + r] * QSCALE;         \
          ik[r] = qkv_b[512 + head * 32 + 16 * d + 4 * lg + r];            \
        }                                                                  \
        _Pragma("unroll") for (int t = 0; t < 4; ++t) {                    \
          accQ[d][t] = iq;                                                 \
          accK[d][t] = ik;                                                 \
        }                                                                  \
      }                                                                    \
      _Pragma("unroll 1") for (int kt = 0; kt < 8; ++kt) {                 \
        h16x8 WQK[8];                                                      \
        WLOAD8(WQK, kt);                                                   \
        STEP_QK(kt, WQK);                                                  \
      }                                                                    \
      _Pragma("unroll") for (int d = 0; d < 2; ++d)                        \
      _Pragma("unroll") for (int t = 0; t < 4; ++t)                        \
      _Pragma("unroll") for (int r = 0; r < 4; ++r) {                      \
        Qh[d][t][r] = (h16)accQ[d][t][r];                                  \
        Kh[d][t][r] = (h16)accK[d][t][r];                                  \
      }                                                                    \
    }                                                                      \
    /* ---- V pass (bias C-init, same xf bytes as A-operand) ---- */ {     \
      f32x4 accV[4][2];                                                    \
      _Pragma("unroll") for (int d = 0; d < 2; ++d) {                      \
        float bv = qkv_b[1024 + head * 32 + 16 * d + l15];                 \
        f32x4 iv = { bv, bv, bv, bv };                                     \
        _Pragma("unroll") for (int t = 0; t < 4; ++t) accV[t][d] = iv;     \
      }                                                                    \
      _Pragma("unroll 1") for (int kt = 0; kt < 8; ++kt) {                 \
        h16x8 WV[4];                                                       \
        WLOAD4V(WV, kt);                                                   \
        STEP_V(kt, WV);                                                    \
      }                                                                    \
      _Pragma("unroll") for (int t = 0; t < 4; ++t)                        \
      _Pragma("unroll") for (int d = 0; d < 2; ++d)                        \
      _Pragma("unroll") for (int r = 0; r < 4; ++r)                        \
        Vh[t][d][r] = (h16)accV[t][d][r];                                  \
    }                                                                      \
    /* S^T = K Q^T with attention-bias fragment as C-init */               \
    f32x4 st[4][4];                                                        \
    __builtin_amdgcn_s_setprio(1);                                         \
    _Pragma("unroll") for (int jt = 0; jt < 4; ++jt)                       \
    _Pragma("unroll") for (int qt = 0; qt < 4; ++qt) {                     \
      float4 bvv = bF4[(head * 16 + qt * 4 + jt) * 64 + lane];             \
      f32x4 c0 = { bvv.x, bvv.y, bvv.z, bvv.w };                           \
      st[jt][qt] = MFMA16(Kh[0][jt], Qh[0][qt], c0);                       \
      st[jt][qt] = MFMA16(Kh[1][jt], Qh[1][qt], st[jt][qt]);               \
    }                                                                      \
    __builtin_amdgcn_s_setprio(0);                                         \
    h16x4 pf[4][4];                                                        \
    _Pragma("unroll") for (int qt = 0; qt < 4; ++qt)                       \
    _Pragma("unroll") for (int jt = 0; jt < 4; ++jt) {                     \
      h16x4 p;                                                             \
      _Pragma("unroll") for (int r = 0; r < 4; ++r)                        \
        p[r] = (h16)exp2f(st[jt][qt][r]);                                  \
      pf[jt][qt] = p;                                                      \
    }                                                                      \
    f32x4 ss[4];                                                           \
    _Pragma("unroll") for (int qt = 0; qt < 4; ++qt)                       \
      ss[qt] = (f32x4){0.f, 0.f, 0.f, 0.f};                                \
    f32x4 ot[2][4];                                                        \
    _Pragma("unroll") for (int d = 0; d < 2; ++d)                          \
    _Pragma("unroll") for (int qt = 0; qt < 4; ++qt)                       \
      ot[d][qt] = (f32x4){0.f, 0.f, 0.f, 0.f};                             \
    __builtin_amdgcn_s_setprio(1);                                         \
    _Pragma("unroll") for (int jt = 0; jt < 4; ++jt)                       \
    _Pragma("unroll") for (int qt = 0; qt < 4; ++qt) {                     \
      ss[qt] = MFMA16(ones, pf[jt][qt], ss[qt]);                           \
      _Pragma("unroll") for (int d = 0; d < 2; ++d)                        \
        ot[d][qt] = MFMA16(Vh[jt][d], pf[jt][qt], ot[d][qt]);              \
    }                                                                      \
    __builtin_amdgcn_s_setprio(0);                                         \
    _Pragma("unroll") for (int qt = 0; qt < 4; ++qt) {                     \
      int q = 16 * qt + l15;                                               \
      float ri = __builtin_amdgcn_rcpf(ss[qt][0]);                         \
      if (q < 49) {                                                        \
        h16* gdst = O + (rowbase + q) * 512 + head * 32 + 4 * lg;          \
        _Pragma("unroll") for (int d = 0; d < 2; ++d) {                    \
          h16x4 ov;                                                        \
          _Pragma("unroll") for (int r = 0; r < 4; ++r)                    \
            ov[r] = (h16)(ot[d][qt][r] * ri);                              \
          *(h16x4*)(gdst + 16 * d) = ov;                                   \
        }                                                                  \
      }                                                                    \
    } }

  PROCESS_HEAD(gp * 2);
  PROCESS_HEAD(gp * 2 + 1);
#undef PROCESS_HEAD
#undef STEP_QK
#undef STEP_V
#undef WLOAD8
#undef WLOAD4V
}

// ---------------- output projection: out = O @ w2 + proj_b ----------------
// 128x128 tile, 4 waves of 64x64, BK=64, x32 MFMAs. A (O tile) staged in LDS
// (swizzled, 16 KiB); B read DIRECTLY from fragment-packed w2F (L2-resident,
// coalesced 1KB wave-loads) -- no B staging.
__global__ __launch_bounds__(256, 3) void wa_proj(
    const h16* __restrict__ O, const h16* __restrict__ w2F,
    const float* __restrict__ proj_b, float* __restrict__ out) {
  __shared__ __align__(16) char lds[16384];   // A: [128 rows][64 k] h16, swizzled
  const int tid = threadIdx.x;
  const int wave = tid >> 6, lane = tid & 63;
  const int l15 = lane & 15, lg = lane >> 4;
  const int lbid = (blockIdx.x & 7) * 784 + (blockIdx.x >> 3);  // XCD swizzle (6272 % 8 == 0)
  const int rowt = lbid >> 2, colt = lbid & 3;
  const int wr = wave >> 1, wc = wave & 1;
  const h16* wb2 = w2F + (size_t)(colt * 2 + wc) * 32768 + lane * 8;

  f32x4 acc[4][4];
  #pragma unroll
  for (int a = 0; a < 4; ++a)
    #pragma unroll
    for (int b = 0; b < 4; ++b) acc[a][b] = (f32x4){0.f, 0.f, 0.f, 0.f};

  h16x8 pre[4];
  #pragma unroll
  for (int p = 0; p < 4; ++p) {          // prologue load A tile 0 (1024 chunks)
    int idx = tid + p * 256;
    int r = idx >> 3, c = idx & 7;
    pre[p] = *(const h16x8*)(O + (size_t)(rowt * 128 + r) * 512 + c * 8);
  }
  #pragma unroll
  for (int p = 0; p < 4; ++p) {
    int idx = tid + p * 256;
    int r = idx >> 3, c = idx & 7;
    *(h16x8*)(lds + r * 128 + ((c ^ (r & 7)) << 4)) = pre[p];
  }
  __syncthreads();

  for (int kt = 0; kt < 8; ++kt) {
    if (kt < 7) {
      #pragma unroll
      for (int p = 0; p < 4; ++p) {
        int idx = tid + p * 256;
        int r = idx >> 3, c = idx & 7;
        pre[p] = *(const h16x8*)(O + (size_t)(rowt * 128 + r) * 512 + (kt + 1) * 64 + c * 8);
      }
    }
    #pragma unroll
    for (int kh = 0; kh < 2; ++kh) {
      const int sw = (l15 & 7);
      h16x8 af[4], bf[4];
      #pragma unroll
      for (int mt = 0; mt < 4; ++mt) {
        int r = wr * 64 + 16 * mt + l15;
        af[mt] = *(const h16x8*)(lds + r * 128 + (((kh * 4 + lg) ^ sw) << 4));
      }
      #pragma unroll
      for (int nt = 0; nt < 4; ++nt)
        bf[nt] = *(const h16x8*)(wb2 + (size_t)(kt * 8 + nt * 2 + kh) * 512);
      __builtin_amdgcn_s_setprio(1);
      #pragma unroll
      for (int mt = 0; mt < 4; ++mt)
        #pragma unroll
        for (int nt = 0; nt < 4; ++nt)
          acc[mt][nt] = MFMA32(af[mt], bf[nt], acc[mt][nt]);
      __builtin_amdgcn_s_setprio(0);
    }
    __syncthreads();
    if (kt < 7) {
      #pragma unroll
      for (int p = 0; p < 4; ++p) {
        int idx = tid + p * 256;
        int r = idx >> 3, c = idx & 7;
        *(h16x8*)(lds + r * 128 + ((c ^ (r & 7)) << 4)) = pre[p];
      }
      __syncthreads();
    }
  }
  #pragma unroll
  for (int nt = 0; nt < 4; ++nt) {
    int col = colt * 128 + wc * 64 + nt * 16 + l15;
    float pb = proj_b[col];
    #pragma unroll
    for (int mt = 0; mt < 4; ++mt) {
      int row = rowt * 128 + wr * 64 + mt * 16 + 4 * lg;
      #pragma unroll
      for (int r = 0; r < 4; ++r)
        out[(size_t)(row + r) * 512 + col] = acc[mt][nt][r] + pb;
    }
  }
}

extern "C" void kernel_launch(void* const* d_in, const int* in_sizes, int n_in,
                              void* d_out, int out_size, void* d_ws, size_t ws_size,
                              hipStream_t stream) {
  const float* x          = (const float*)d_in[0];
  const float* qkv_w      = (const float*)d_in[1];
  const float* qkv_b      = (const float*)d_in[2];
  const float* proj_w     = (const float*)d_in[3];
  const float* proj_b     = (const float*)d_in[4];
  const float* bias_table = (const float*)d_in[5];
  float* out = (float*)d_out;

  char* ws = (char*)d_ws;
  h16*   O     = (h16*)ws;
  h16*   w1F   = (h16*)(ws + W1F_OFF);
  h16*   w2F   = (h16*)(ws + W2F_OFF);
  float* biasF = (float*)(ws + BF_OFF);

  wa_prep<<<576, 256, 0, stream>>>(qkv_w, proj_w, bias_table, w1F, w2F, biasF);
  wa_qkv_attn<<<8192, 256, 0, stream>>>(x, qkv_b, w1F, biasF, O);
  wa_proj<<<1568 * 4, 256, 0, stream>>>(O, w2F, proj_b, out);
}

// Round 16
// 685.420 us; speedup vs baseline: 1.0229x; 1.0157x over previous
//
#include <hip/hip_runtime.h>

typedef _Float16 h16;
typedef __attribute__((ext_vector_type(4))) _Float16 h16x4;
typedef __attribute__((ext_vector_type(8))) _Float16 h16x8;
typedef __attribute__((ext_vector_type(4))) float f32x4;

#define QSCALE 0.25505653882616254f   // 32^-0.5 * log2(e)  (folded into Wq, bq)
#define LOG2E  1.4426950408889634f    // folded into biasF
#define MFMA16(a, b, c) __builtin_amdgcn_mfma_f32_16x16x16f16(a, b, c, 0, 0, 0)
#define MFMA32(a, b, c) __builtin_amdgcn_mfma_f32_16x16x32_f16(a, b, c, 0, 0, 0)

// workspace layout (bytes)
#define O_BYTES 205520896ULL              // 200704*512*2 (pre-proj output, fp16)
#define W1F_OFF (O_BYTES)                 // w1F fp16 fragment-packed: 1572864
#define W2F_OFF (W1F_OFF + 1572864ULL)    // w2F fp16 fragment-packed: 524288
#define BF_OFF  (W2F_OFF + 524288ULL)     // biasF f32 frag-packed [16][4qt][4jt][64lane]x4: 262144

// ---------------- fused prep: w2 fragment-pack | w1 fragment-pack | bias fragment-pack ----------------
__global__ __launch_bounds__(256) void wa_prep(
    const float* __restrict__ qkv_w, const float* __restrict__ proj_w,
    const float* __restrict__ table,
    h16* __restrict__ w1F, h16* __restrict__ w2F, float* __restrict__ biasF) {
  const int b = blockIdx.x, tid = threadIdx.x;
  if (b < 128) {
    int chunk = b * 256 + tid;                  // 32768 chunks
    int lane = chunk & 63;
    int rest = chunk >> 6;
    int fr = rest & 7, kt = (rest >> 3) & 7, cw = rest >> 6;
    int nt = fr >> 1, kh = fr & 1;
    int l15 = lane & 15, lg = lane >> 4;
    int o = cw * 64 + nt * 16 + l15;
    int k0 = kt * 64 + (kh * 4 + lg) * 8;
    h16x8 v;
    #pragma unroll
    for (int e = 0; e < 8; ++e)
      v[e] = (h16)proj_w[(size_t)(k0 + e) * 512 + o];
    *(h16x8*)(w2F + (size_t)chunk * 8) = v;
  } else if (b < 512) {
    int chunk = (b - 128) * 256 + tid;          // 98304 chunks
    int lane = chunk & 63;
    int rest = chunk >> 6;
    int f  = rest % 12;
    int kt = (rest / 12) & 7;
    int wv = (rest / 96) & 3;
    int g  = rest / 384;
    int s = f >> 2, d = (f >> 1) & 1, ks = f & 1;
    int l15 = lane & 15, lg = lane >> 4;
    int o = s * 512 + g * 128 + wv * 32 + d * 16 + l15;
    int k0 = kt * 64 + ks * 32 + lg * 8;
    float sc = (s == 0) ? QSCALE : 1.0f;
    h16x8 v;
    #pragma unroll
    for (int e = 0; e < 8; ++e)
      v[e] = (h16)(qkv_w[(size_t)(k0 + e) * 1536 + o] * sc);
    *(h16x8*)(w1F + (size_t)chunk * 8) = v;
  } else {
    int t = (b - 512) * 256 + tid;              // 16384 float4s
    int lane = t & 63, jt = (t >> 6) & 3, qt = (t >> 8) & 3, head = t >> 10;
    int l15 = lane & 15, lg = lane >> 4;
    int q = qt * 16 + l15;
    float4 v;
    #pragma unroll
    for (int r = 0; r < 4; ++r) {
      int j = jt * 16 + lg * 4 + r;
      float val = -1e30f;
      if (j < 49 && q < 49) {
        int rel = (q / 7 - j / 7 + 6) * 13 + (q % 7 - j % 7 + 6);
        val = table[rel * 16 + head] * LOG2E;
      }
      ((float*)&v)[r] = val;
    }
    ((float4*)biasF)[t] = v;
  }
}

// ---------------- fused QKV projection + window attention ----------------
// grid: 4096 windows (XCD-swizzled); block 256 = 4 waves; each block runs ALL FOUR
// head-groups via a #pragma unroll 1 loop over ONE X staging (X staged once/window;
// r15 staged twice). 49 real rows only (50176 B LDS); t=3 frag rows clamp to row 48
// (pad tokens = token-48 copies, annihilated by -1e30 bias + q<49 store mask).
// Two GEMM passes per head: merged Q+K (shared xf), then V (same xf bytes as
// A-operand), W single-buffered (r13: dbuf spilled; L2 latency covered by 3-deep TLP).
// ALL biases folded into MFMA C-inits. Softmax: max-free exp2 (log2e pre-folded),
// row-sum via all-ones-A MFMA, rcp, direct O^T fragment stores. One barrier total.
// SPILL TRIPWIRE: WRITE_SIZE ~204 MB. 3 blocks/CU (512 regs/SIMD pool, ~150/wave;
// r10 lesson: (256,3) caps waves at ~170 regs -- body must stay under).
__global__ __launch_bounds__(256, 3) void wa_qkv_attn(
    const float* __restrict__ x, const float* __restrict__ qkv_b,
    const h16* __restrict__ w1F, const float* __restrict__ biasF,
    h16* __restrict__ O) {
  __shared__ __align__(16) char lds[50176];   // X: [49 rows][64 chunks of 16B], swizzled
  const int tid = threadIdx.x;
  const int wave = tid >> 6, lane = tid & 63;
  const int l15 = lane & 15, lg = lane >> 4;
  const int sw = l15 & 7;
  const int w = (blockIdx.x & 7) * 512 + (blockIdx.x >> 3);  // XCD swizzle (4096 % 8 == 0)
  const size_t rowbase = (size_t)w * 49;

  // ---- stage X: rows 0..48 fp32 -> fp16 swizzled (no pad rows) ----
  #pragma unroll
  for (int p = 0; p < 13; ++p) {
    int idx = tid + p * 256;
    if (idx < 3136) {
      int r = idx >> 6, c = idx & 63;
      const float* src = x + (rowbase + r) * 512 + c * 8;
      float4 a = *(const float4*)(src);
      float4 bb = *(const float4*)(src + 4);
      h16x8 h = { (h16)a.x, (h16)a.y, (h16)a.z, (h16)a.w,
                  (h16)bb.x, (h16)bb.y, (h16)bb.z, (h16)bb.w };
      *(h16x8*)(lds + r * 1024 + ((c ^ (r & 7)) << 4)) = h;
    }
  }
  __syncthreads();   // the only barrier in the kernel

  // per-lane X read byte-offsets; t=3 clamps to row 48 (swizzle key 48&7 == 0)
  int xbA[4], xbB[4];
  #pragma unroll
  for (int t = 0; t < 4; ++t) {
    int row = (t < 3) ? (16 * t + l15) : 48;
    int swt = (t < 3) ? sw : 0;
    xbA[t] = row * 1024 + ((lg ^ swt) << 4);
    xbB[t] = row * 1024 + (((4 + lg) ^ swt) << 4);
  }
  const h16x4 ones = (h16x4){(h16)1.f, (h16)1.f, (h16)1.f, (h16)1.f};
  const float4* bF4 = (const float4*)biasF;

#define WLOAD8(DST, KT) {                                                  \
    _Pragma("unroll") for (int f8 = 0; f8 < 8; ++f8)                       \
      DST[f8] = *(const h16x8*)(wb + (size_t)(KT) * 6144 + f8 * 512); }

#define WLOAD4V(DST, KT) {                                                 \
    _Pragma("unroll") for (int f4 = 0; f4 < 4; ++f4)                       \
      DST[f4] = *(const h16x8*)(wb + (size_t)(KT) * 6144 + (8 + f4) * 512); }

#define STEP_QK(KT, W) {                                                   \
    h16x8 xf[4];                                                           \
    _Pragma("unroll") for (int t = 0; t < 4; ++t)                          \
      xf[t] = *(const h16x8*)(lds + xbA[t] + (KT) * 128);                  \
    __builtin_amdgcn_s_setprio(1);                                         \
    _Pragma("unroll") for (int d = 0; d < 2; ++d)                          \
    _Pragma("unroll") for (int t = 0; t < 4; ++t) {                        \
      accQ[d][t] = MFMA32(W[d*2],     xf[t], accQ[d][t]);                  \
      accK[d][t] = MFMA32(W[4 + d*2], xf[t], accK[d][t]);                  \
    }                                                                      \
    __builtin_amdgcn_s_setprio(0);                                         \
    _Pragma("unroll") for (int t = 0; t < 4; ++t)                          \
      xf[t] = *(const h16x8*)(lds + xbB[t] + (KT) * 128);                  \
    __builtin_amdgcn_s_setprio(1);                                         \
    _Pragma("unroll") for (int d = 0; d < 2; ++d)                          \
    _Pragma("unroll") for (int t = 0; t < 4; ++t) {                        \
      accQ[d][t] = MFMA32(W[d*2 + 1],     xf[t], accQ[d][t]);              \
      accK[d][t] = MFMA32(W[4 + d*2 + 1], xf[t], accK[d][t]);              \
    }                                                                      \
    __builtin_amdgcn_s_setprio(0); }

#define STEP_V(KT, W) {                                                    \
    h16x8 xf[4];                                                           \
    _Pragma("unroll") for (int t = 0; t < 4; ++t)                          \
      xf[t] = *(const h16x8*)(lds + xbA[t] + (KT) * 128);                  \
    __builtin_amdgcn_s_setprio(1);                                         \
    _Pragma("unroll") for (int d = 0; d < 2; ++d)                          \
    _Pragma("unroll") for (int t = 0; t < 4; ++t)                          \
      accV[t][d] = MFMA32(xf[t], W[d*2], accV[t][d]);                      \
    __builtin_amdgcn_s_setprio(0);                                         \
    _Pragma("unroll") for (int t = 0; t < 4; ++t)                          \
      xf[t] = *(const h16x8*)(lds + xbB[t] + (KT) * 128);                  \
    __builtin_amdgcn_s_setprio(1);                                         \
    _Pragma("unroll") for (int d = 0; d < 2; ++d)                          \
    _Pragma("unroll") for (int t = 0; t < 4; ++t)                          \
      accV[t][d] = MFMA32(xf[t], W[d*2 + 1], accV[t][d]);                  \
    __builtin_amdgcn_s_setprio(0); }

  #pragma unroll 1
  for (int g = 0; g < 4; ++g) {
    const int head = g * 4 + wave;
    const h16* wb = w1F + ((size_t)(g * 4 + wave) * 8) * 6144 + lane * 8;
    h16x4 Qh[2][4], Kh[2][4], Vh[4][2];

    // ---- merged Q+K pass (bias C-init, shared xf, single-buffered W) ----
    {
      f32x4 accQ[2][4], accK[2][4];
      #pragma unroll
      for (int d = 0; d < 2; ++d) {
        f32x4 iq, ik;
        #pragma unroll
        for (int r = 0; r < 4; ++r) {
          iq[r] = qkv_b[head * 32 + 16 * d + 4 * lg + r] * QSCALE;
          ik[r] = qkv_b[512 + head * 32 + 16 * d + 4 * lg + r];
        }
        #pragma unroll
        for (int t = 0; t < 4; ++t) {
          accQ[d][t] = iq;
          accK[d][t] = ik;
        }
      }
      #pragma unroll 1
      for (int kt = 0; kt < 8; ++kt) {
        h16x8 WQK[8];
        WLOAD8(WQK, kt);
        STEP_QK(kt, WQK);
      }
      #pragma unroll
      for (int d = 0; d < 2; ++d)
        #pragma unroll
        for (int t = 0; t < 4; ++t)
          #pragma unroll
          for (int r = 0; r < 4; ++r) {
            Qh[d][t][r] = (h16)accQ[d][t][r];
            Kh[d][t][r] = (h16)accK[d][t][r];
          }
    }

    // ---- V pass (bias C-init, same xf bytes as A-operand) ----
    {
      f32x4 accV[4][2];
      #pragma unroll
      for (int d = 0; d < 2; ++d) {
        float bv = qkv_b[1024 + head * 32 + 16 * d + l15];
        f32x4 iv = { bv, bv, bv, bv };
        #pragma unroll
        for (int t = 0; t < 4; ++t) accV[t][d] = iv;
      }
      #pragma unroll 1
      for (int kt = 0; kt < 8; ++kt) {
        h16x8 WV[4];
        WLOAD4V(WV, kt);
        STEP_V(kt, WV);
      }
      #pragma unroll
      for (int t = 0; t < 4; ++t)
        #pragma unroll
        for (int d = 0; d < 2; ++d)
          #pragma unroll
          for (int r = 0; r < 4; ++r)
            Vh[t][d][r] = (h16)accV[t][d][r];
    }

    // ---- S^T = K Q^T with attention-bias fragment as C-init ----
    f32x4 st[4][4];
    __builtin_amdgcn_s_setprio(1);
    #pragma unroll
    for (int jt = 0; jt < 4; ++jt)
      #pragma unroll
      for (int qt = 0; qt < 4; ++qt) {
        float4 bvv = bF4[(head * 16 + qt * 4 + jt) * 64 + lane];
        f32x4 c0 = { bvv.x, bvv.y, bvv.z, bvv.w };
        st[jt][qt] = MFMA16(Kh[0][jt], Qh[0][qt], c0);
        st[jt][qt] = MFMA16(Kh[1][jt], Qh[1][qt], st[jt][qt]);
      }
    __builtin_amdgcn_s_setprio(0);

    // ---- P = exp2(S') ----
    h16x4 pf[4][4];
    #pragma unroll
    for (int qt = 0; qt < 4; ++qt)
      #pragma unroll
      for (int jt = 0; jt < 4; ++jt) {
        h16x4 p;
        #pragma unroll
        for (int r = 0; r < 4; ++r)
          p[r] = (h16)exp2f(st[jt][qt][r]);
        pf[jt][qt] = p;
      }

    // ---- row sums via all-ones-A MFMA + O^T = V^T P^T ----
    f32x4 ss[4];
    #pragma unroll
    for (int qt = 0; qt < 4; ++qt) ss[qt] = (f32x4){0.f, 0.f, 0.f, 0.f};
    f32x4 ot[2][4];
    #pragma unroll
    for (int d = 0; d < 2; ++d)
      #pragma unroll
      for (int qt = 0; qt < 4; ++qt) ot[d][qt] = (f32x4){0.f, 0.f, 0.f, 0.f};
    __builtin_amdgcn_s_setprio(1);
    #pragma unroll
    for (int jt = 0; jt < 4; ++jt)
      #pragma unroll
      for (int qt = 0; qt < 4; ++qt) {
        ss[qt] = MFMA16(ones, pf[jt][qt], ss[qt]);
        #pragma unroll
        for (int d = 0; d < 2; ++d)
          ot[d][qt] = MFMA16(Vh[jt][d], pf[jt][qt], ot[d][qt]);
      }
    __builtin_amdgcn_s_setprio(0);

    // ---- normalize + direct O^T fragment stores (q < 49) ----
    #pragma unroll
    for (int qt = 0; qt < 4; ++qt) {
      int q = 16 * qt + l15;
      float ri = __builtin_amdgcn_rcpf(ss[qt][0]);
      if (q < 49) {
        h16* gdst = O + (rowbase + q) * 512 + head * 32 + 4 * lg;
        #pragma unroll
        for (int d = 0; d < 2; ++d) {
          h16x4 ov;
          #pragma unroll
          for (int r = 0; r < 4; ++r) ov[r] = (h16)(ot[d][qt][r] * ri);
          *(h16x4*)(gdst + 16 * d) = ov;
        }
      }
    }
  }
#undef STEP_QK
#undef STEP_V
#undef WLOAD8
#undef WLOAD4V
}

// ---------------- output projection: out = O @ w2 + proj_b ----------------
// 128x128 tile, 4 waves of 64x64, BK=64, x32 MFMAs. A (O tile) staged in LDS
// (swizzled, 16 KiB); B read DIRECTLY from fragment-packed w2F (L2-resident,
// coalesced 1KB wave-loads) -- no B staging.
__global__ __launch_bounds__(256, 3) void wa_proj(
    const h16* __restrict__ O, const h16* __restrict__ w2F,
    const float* __restrict__ proj_b, float* __restrict__ out) {
  __shared__ __align__(16) char lds[16384];   // A: [128 rows][64 k] h16, swizzled
  const int tid = threadIdx.x;
  const int wave = tid >> 6, lane = tid & 63;
  const int l15 = lane & 15, lg = lane >> 4;
  const int lbid = (blockIdx.x & 7) * 784 + (blockIdx.x >> 3);  // XCD swizzle (6272 % 8 == 0)
  const int rowt = lbid >> 2, colt = lbid & 3;
  const int wr = wave >> 1, wc = wave & 1;
  const h16* wb2 = w2F + (size_t)(colt * 2 + wc) * 32768 + lane * 8;

  f32x4 acc[4][4];
  #pragma unroll
  for (int a = 0; a < 4; ++a)
    #pragma unroll
    for (int b = 0; b < 4; ++b) acc[a][b] = (f32x4){0.f, 0.f, 0.f, 0.f};

  h16x8 pre[4];
  #pragma unroll
  for (int p = 0; p < 4; ++p) {          // prologue load A tile 0 (1024 chunks)
    int idx = tid + p * 256;
    int r = idx >> 3, c = idx & 7;
    pre[p] = *(const h16x8*)(O + (size_t)(rowt * 128 + r) * 512 + c * 8);
  }
  #pragma unroll
  for (int p = 0; p < 4; ++p) {
    int idx = tid + p * 256;
    int r = idx >> 3, c = idx & 7;
    *(h16x8*)(lds + r * 128 + ((c ^ (r & 7)) << 4)) = pre[p];
  }
  __syncthreads();

  for (int kt = 0; kt < 8; ++kt) {
    if (kt < 7) {
      #pragma unroll
      for (int p = 0; p < 4; ++p) {
        int idx = tid + p * 256;
        int r = idx >> 3, c = idx & 7;
        pre[p] = *(const h16x8*)(O + (size_t)(rowt * 128 + r) * 512 + (kt + 1) * 64 + c * 8);
      }
    }
    #pragma unroll
    for (int kh = 0; kh < 2; ++kh) {
      const int sw = (l15 & 7);
      h16x8 af[4], bf[4];
      #pragma unroll
      for (int mt = 0; mt < 4; ++mt) {
        int r = wr * 64 + 16 * mt + l15;
        af[mt] = *(const h16x8*)(lds + r * 128 + (((kh * 4 + lg) ^ sw) << 4));
      }
      #pragma unroll
      for (int nt = 0; nt < 4; ++nt)
        bf[nt] = *(const h16x8*)(wb2 + (size_t)(kt * 8 + nt * 2 + kh) * 512);
      __builtin_amdgcn_s_setprio(1);
      #pragma unroll
      for (int mt = 0; mt < 4; ++mt)
        #pragma unroll
        for (int nt = 0; nt < 4; ++nt)
          acc[mt][nt] = MFMA32(af[mt], bf[nt], acc[mt][nt]);
      __builtin_amdgcn_s_setprio(0);
    }
    __syncthreads();
    if (kt < 7) {
      #pragma unroll
      for (int p = 0; p < 4; ++p) {
        int idx = tid + p * 256;
        int r = idx >> 3, c = idx & 7;
        *(h16x8*)(lds + r * 128 + ((c ^ (r & 7)) << 4)) = pre[p];
      }
      __syncthreads();
    }
  }
  #pragma unroll
  for (int nt = 0; nt < 4; ++nt) {
    int col = colt * 128 + wc * 64 + nt * 16 + l15;
    float pb = proj_b[col];
    #pragma unroll
    for (int mt = 0; mt < 4; ++mt) {
      int row = rowt * 128 + wr * 64 + mt * 16 + 4 * lg;
      #pragma unroll
      for (int r = 0; r < 4; ++r)
        out[(size_t)(row + r) * 512 + col] = acc[mt][nt][r] + pb;
    }
  }
}

extern "C" void kernel_launch(void* const* d_in, const int* in_sizes, int n_in,
                              void* d_out, int out_size, void* d_ws, size_t ws_size,
                              hipStream_t stream) {
  const float* x          = (const float*)d_in[0];
  const float* qkv_w      = (const float*)d_in[1];
  const float* qkv_b      = (const float*)d_in[2];
  const float* proj_w     = (const float*)d_in[3];
  const float* proj_b     = (const float*)d_in[4];
  const float* bias_table = (const float*)d_in[5];
  float* out = (float*)d_out;

  char* ws = (char*)d_ws;
  h16*   O     = (h16*)ws;
  h16*   w1F   = (h16*)(ws + W1F_OFF);
  h16*   w2F   = (h16*)(ws + W2F_OFF);
  float* biasF = (float*)(ws + BF_OFF);

  wa_prep<<<576, 256, 0, stream>>>(qkv_w, proj_w, bias_table, w1F, w2F, biasF);
  wa_qkv_attn<<<4096, 256, 0, stream>>>(x, qkv_b, w1F, biasF, O);
  wa_proj<<<1568 * 4, 256, 0, stream>>>(O, w2F, proj_b, out);
}